// Round 1
// baseline (269.141 us; speedup 1.0000x reference)
//
#include <hip/hip_runtime.h>
#include <hip/hip_bf16.h>
#include <math.h>

#define Bsz  2
#define Nseq 1536
#define Dmod 1024
#define NH   16
#define DHd  64
#define MTOT (Bsz*Nseq)          // 3072
#define SCALE 0.125f             // DH^-0.5
#define BK   32

typedef short  short8 __attribute__((ext_vector_type(8)));
typedef float  f32x4  __attribute__((ext_vector_type(4)));
typedef unsigned short u16x4 __attribute__((ext_vector_type(4)));
typedef unsigned short ushortT;

__device__ __forceinline__ float b2f(__hip_bfloat16 v) { return __bfloat162float(v); }
__device__ __forceinline__ unsigned short f2bf(float f) {   // RNE f32->bf16
    union { float f; unsigned u; } a; a.f = f;
    unsigned r = a.u + 0x7fffu + ((a.u >> 16) & 1u);
    return (unsigned short)(r >> 16);
}

// async global->LDS, 16B per lane (wave-uniform base + lane*16)
__device__ __forceinline__ void gl2lds16(const ushortT* g, ushortT* lds) {
    __builtin_amdgcn_global_load_lds(
        (const __attribute__((address_space(1))) unsigned int*)(g),
        (__attribute__((address_space(3))) unsigned int*)(lds),
        16, 0, 0);
}

// ---------------------------------------------------------------------------
// prep: z<5 -> W f32 [k][n] -> Wt bf16 [n][k] transpose (float4 reads,
// u16x4 stores);  z==5 -> x f32->bf16 (grid-stride) + zero gate_logit.
// ---------------------------------------------------------------------------
__global__ __launch_bounds__(256)
void prep_kernel(const float* W0, const float* W1, const float* W2,
                 const float* W3, const float* W4,
                 ushortT* T0, ushortT* T1, ushortT* T2, ushortT* T3, ushortT* T4,
                 const float* __restrict__ x, ushortT* __restrict__ xb,
                 float* __restrict__ glogit)
{
    const int z = blockIdx.z;
    const int t = threadIdx.x;
    if (z == 5) {
        const int bi = blockIdx.y * 16 + blockIdx.x;   // 0..255
        const size_t NEl = (size_t)MTOT * Dmod;
        for (size_t i = ((size_t)bi * 256 + t) * 4; i < NEl; i += (size_t)256 * 256 * 4) {
            float4 v = *(const float4*)(x + i);
            u16x4 o = { f2bf(v.x), f2bf(v.y), f2bf(v.z), f2bf(v.w) };
            *(u16x4*)(xb + i) = o;
        }
        if (t < 12) glogit[bi * 12 + t] = 0.f;
        return;
    }
    __shared__ float tile[64][65];
    const float* W = z == 0 ? W0 : z == 1 ? W1 : z == 2 ? W2 : z == 3 ? W3 : W4;
    ushortT*     T = z == 0 ? T0 : z == 1 ? T1 : z == 2 ? T2 : z == 3 ? T3 : T4;
    const int k0 = blockIdx.x * 64, n0 = blockIdx.y * 64;
    for (int i = t; i < 1024; i += 256) {            // 64 rows x 16 col-groups
        int r = i >> 4, c4 = (i & 15) * 4;
        float4 v = *(const float4*)&W[(size_t)(k0 + r) * 1024 + n0 + c4];
        tile[r][c4 + 0] = v.x; tile[r][c4 + 1] = v.y;
        tile[r][c4 + 2] = v.z; tile[r][c4 + 3] = v.w;
    }
    __syncthreads();
    for (int i = t; i < 1024; i += 256) {            // 64 n-rows x 16 k-groups
        int rn = i >> 4, ck4 = (i & 15) * 4;
        u16x4 o = { f2bf(tile[ck4 + 0][rn]), f2bf(tile[ck4 + 1][rn]),
                    f2bf(tile[ck4 + 2][rn]), f2bf(tile[ck4 + 3][rn]) };
        *(u16x4*)&T[(size_t)(n0 + rn) * 1024 + k0 + ck4] = o;
    }
}

// ---------------------------------------------------------------------------
// R10: fused QKVG GEMM, 256x256 tile, BK=64, 8 waves (2Mx4N), 4-phase
// schedule per K-tile (ported 8-phase/2-tile template: T1 xcd-swizzle +
// T2 lds-xor-swizzle + T3/T4 counted-vmcnt phases + T5 setprio).
//   - B fused: WtQ|WtK|WtV|WtG contiguous in ws -> one [4096][1024] operand.
//   - Wave frag ownership INTERLEAVED (m = f*32 + wr*16, n = j*64 + wc*16) so
//     phase-1 frags of every wave live in tile-half 0 (phase/half alignment).
//   - LDS 128KB: As[2][256*64] + Bs[2][256*64]; 1 block/CU, 2 waves/SIMD.
//   - Swizzle: LDS row r (128B), 16B slot s holds global k-chunk s^(r&7).
//     Staged via pre-swizzled GLOBAL source (gl_lds dest must stay linear);
//     read side applies the same XOR (both-sides rule).
//   - Stage order per tile t (for t+1): P1:A0 P2:B0 P3:B1 P4:A1 (2 loads ea).
//     Waits: vmcnt(4) at end of P1,P2,P4 (never 0 in steady state; in-flight
//     4..8). Last tile: vmcnt(2)/vmcnt(0) at P1/P2 end.
//   [R9 note kept: 128x128 ping-pong on the OLD 2-phase structure regressed;
//    this is the full phase-schedule port, not a tile-size retry.]
// ---------------------------------------------------------------------------
#define MFMA16(a, b, c) __builtin_amdgcn_mfma_f32_16x16x32_bf16((a), (b), (c), 0, 0, 0)

__global__ __launch_bounds__(512, 2)
void gemm_qkvg(const ushortT* __restrict__ xb, const ushortT* __restrict__ Wt,
               const float* __restrict__ bz0, const float* __restrict__ bz1,
               const float* __restrict__ bz2, const float* __restrict__ bz3,
               const float* __restrict__ Wg2,
               ushortT* __restrict__ O0, ushortT* __restrict__ O1,
               ushortT* __restrict__ O2, float* __restrict__ glogit)
{
    __shared__ ushortT As[2][256 * 64];   // 64 KB
    __shared__ ushortT Bs[2][256 * 64];   // 64 KB

    // T1: XCD-aware bijective remap (192 blocks, 192 % 8 == 0)
    const int bid = blockIdx.y * 16 + blockIdx.x;
    const int wg  = (bid & 7) * 24 + (bid >> 3);
    const int bx = wg & 15, by = wg >> 4;
    const int m0 = by * 256, n0 = bx * 256;

    const int t = threadIdx.x;
    const int l = t & 63, w = t >> 6;
    const int wr = w >> 2, wc = w & 3;            // 2 x 4 waves
    const int lm = l & 15, q4 = l >> 4;

    // staging: thread t covers row (strip*64 + tr), swizzled k-chunk sg
    const int tr = t >> 3;                         // 0..63
    const int sg = ((t & 7) ^ (tr & 7)) * 8;       // pre-swizzled source chunk
    const ushortT* Asrc = xb + (size_t)(m0 + tr) * 1024 + sg;
    const ushortT* Bsrc = Wt + (size_t)(n0 + tr) * 1024 + sg;

#define STG_A(buf, s, k_) gl2lds16(Asrc + (size_t)(s) * 64 * 1024 + (k_), &As[buf][(s) * 4096 + t * 8])
#define STG_B(buf, s, k_) gl2lds16(Bsrc + (size_t)(s) * 64 * 1024 + (k_), &Bs[buf][(s) * 4096 + t * 8])

    // ds_read frag addressing (swizzled): row*64 + ((kk*4+q4)^(lm&7))*8
    const int slot0 = (q4 ^ (lm & 7)) * 8;         // kk=0;  kk=1 -> slot0^32
    const int aOff  = (wr * 16 + lm) * 64;         // + f*2048 (f*32 rows)
    const int bOff  = (wc * 16 + lm) * 64;         // + j*4096 (j*64 rows)

#define RDA(buf, f, kk) (*(const short8*)&As[buf][aOff + (f) * 2048 + (slot0 ^ ((kk) * 32))])
#define RDB(buf, j, kk) (*(const short8*)&Bs[buf][bOff + (j) * 4096 + (slot0 ^ ((kk) * 32))])

    f32x4 acc[8][4] = {};
    short8 afr[4][2], bfr[4][2];

    // ---- prologue: stage tile 0 in order A0,B0,B1,A1; wait oldest 4 ----
    STG_A(0, 0, 0); STG_A(0, 1, 0);
    STG_B(0, 0, 0); STG_B(0, 1, 0);
    STG_B(0, 2, 0); STG_B(0, 3, 0);
    STG_A(0, 2, 0); STG_A(0, 3, 0);
    asm volatile("s_waitcnt vmcnt(4)" ::: "memory");
    __builtin_amdgcn_s_barrier();

    for (int kt = 0; kt < 16; ++kt) {
        const int cur = kt & 1, nxt = cur ^ 1;
        const int kN = (kt + 1) * 64;
        const bool more = (kt < 15);

        // ===== P1: read A-half0 (f0..3) + B-half0 (j0..1); stage A0(next) =====
#pragma unroll
        for (int f = 0; f < 4; ++f) { afr[f][0] = RDA(cur, f, 0); afr[f][1] = RDA(cur, f, 1); }
#pragma unroll
        for (int j = 0; j < 2; ++j) { bfr[j][0] = RDB(cur, j, 0); bfr[j][1] = RDB(cur, j, 1); }
        if (more) { STG_A(nxt, 0, kN); STG_A(nxt, 1, kN); }
        __builtin_amdgcn_s_barrier();
        asm volatile("s_waitcnt lgkmcnt(0)" ::: "memory");
        __builtin_amdgcn_sched_barrier(0);
        __builtin_amdgcn_s_setprio(1);
#pragma unroll
        for (int f = 0; f < 4; ++f)
#pragma unroll
            for (int j = 0; j < 2; ++j) {
                acc[f][j] = MFMA16(afr[f][0], bfr[j][0], acc[f][j]);
                acc[f][j] = MFMA16(afr[f][1], bfr[j][1], acc[f][j]);
            }
        __builtin_amdgcn_s_setprio(0);
        __builtin_amdgcn_sched_barrier(0);
        if (more) asm volatile("s_waitcnt vmcnt(4)" ::: "memory");   // drains B1(t)
        else      asm volatile("s_waitcnt vmcnt(2)" ::: "memory");
        __builtin_amdgcn_s_barrier();

        // ===== P2: read B-half1 (j2..3); stage B0(next) =====
#pragma unroll
        for (int j = 2; j < 4; ++j) { bfr[j][0] = RDB(cur, j, 0); bfr[j][1] = RDB(cur, j, 1); }
        if (more) { STG_B(nxt, 0, kN); STG_B(nxt, 1, kN); }
        __builtin_amdgcn_s_barrier();
        asm volatile("s_waitcnt lgkmcnt(0)" ::: "memory");
        __builtin_amdgcn_sched_barrier(0);
        __builtin_amdgcn_s_setprio(1);
#pragma unroll
        for (int f = 0; f < 4; ++f)
#pragma unroll
            for (int j = 2; j < 4; ++j) {
                acc[f][j] = MFMA16(afr[f][0], bfr[j][0], acc[f][j]);
                acc[f][j] = MFMA16(afr[f][1], bfr[j][1], acc[f][j]);
            }
        __builtin_amdgcn_s_setprio(0);
        __builtin_amdgcn_sched_barrier(0);
        if (more) asm volatile("s_waitcnt vmcnt(4)" ::: "memory");   // drains A1(t)
        else      asm volatile("s_waitcnt vmcnt(0)" ::: "memory");
        __builtin_amdgcn_s_barrier();

        // ===== P3: read A-half1 (f4..7, reuse afr); stage B1(next) =====
#pragma unroll
        for (int f = 0; f < 4; ++f) { afr[f][0] = RDA(cur, f + 4, 0); afr[f][1] = RDA(cur, f + 4, 1); }
        if (more) { STG_B(nxt, 2, kN); STG_B(nxt, 3, kN); }
        __builtin_amdgcn_s_barrier();
        asm volatile("s_waitcnt lgkmcnt(0)" ::: "memory");
        __builtin_amdgcn_sched_barrier(0);
        __builtin_amdgcn_s_setprio(1);
#pragma unroll
        for (int f = 0; f < 4; ++f)
#pragma unroll
            for (int j = 2; j < 4; ++j) {
                acc[f + 4][j] = MFMA16(afr[f][0], bfr[j][0], acc[f + 4][j]);
                acc[f + 4][j] = MFMA16(afr[f][1], bfr[j][1], acc[f + 4][j]);
            }
        __builtin_amdgcn_s_setprio(0);
        __builtin_amdgcn_s_barrier();                                // no vmcnt

        // ===== P4: no reads; stage A1(next) =====
        if (more) { STG_A(nxt, 2, kN); STG_A(nxt, 3, kN); }
        __builtin_amdgcn_s_barrier();
        __builtin_amdgcn_s_setprio(1);
#pragma unroll
        for (int f = 0; f < 4; ++f)
#pragma unroll
            for (int j = 0; j < 2; ++j) {
                acc[f + 4][j] = MFMA16(afr[f][0], bfr[j][0], acc[f + 4][j]);
                acc[f + 4][j] = MFMA16(afr[f][1], bfr[j][1], acc[f + 4][j]);
            }
        __builtin_amdgcn_s_setprio(0);
        __builtin_amdgcn_sched_barrier(0);
        if (more) asm volatile("s_waitcnt vmcnt(4)" ::: "memory");   // drains A0,B0(t+1)
        __builtin_amdgcn_s_barrier();
    }

    // ---- epilogue: m = m0 + f*32 + wr*16 + q4*4 + r ; n = n0 + j*64 + wc*16 + lm
    const int z = bx >> 2;
    if (z == 3) {       // gate: gelu -> dot Wg2 -> atomicAdd glogit[m]
        float part[8][4] = {};
#pragma unroll
        for (int f = 0; f < 8; ++f)
#pragma unroll
            for (int j = 0; j < 4; ++j) {
                int nn = (n0 & 1023) + j * 64 + wc * 16 + lm;
                float bn = bz3[nn], w2 = Wg2[nn];
#pragma unroll
                for (int r = 0; r < 4; ++r) {
                    float v = acc[f][j][r] + bn;
                    v = 0.5f * v * (1.0f + erff(v * 0.70710678118654752f));
                    part[f][r] += v * w2;
                }
            }
#pragma unroll
        for (int f = 0; f < 8; ++f)
#pragma unroll
            for (int r = 0; r < 4; ++r) {
                float p = part[f][r];
#pragma unroll
                for (int msk = 1; msk < 16; msk <<= 1) p += __shfl_xor(p, msk, 16);
                if (lm == 0)
                    atomicAdd(&glogit[m0 + f * 32 + wr * 16 + q4 * 4 + r], p);
            }
        return;
    }
    const float* bias = z == 0 ? bz0 : z == 1 ? bz1 : bz2;
    ushortT* O = z == 0 ? O0 : z == 1 ? O1 : O2;
#pragma unroll
    for (int f = 0; f < 8; ++f)
#pragma unroll
        for (int j = 0; j < 4; ++j) {
            int nn = (n0 & 1023) + j * 64 + wc * 16 + lm;
            float bn = bias[nn];
#pragma unroll
            for (int r = 0; r < 4; ++r) {
                int m = m0 + f * 32 + wr * 16 + q4 * 4 + r;
                float v = acc[f][j][r] + bn;
                if (z == 0) v *= SCALE;
                if (z == 2) {  // Vt[((b*16+h)*64+dd)*1536 + nn2]
                    int bb = m >= Nseq ? 1 : 0, nn2 = m - bb * Nseq;
                    int h = nn >> 6, dd = nn & 63;
                    O[(size_t)((bb * 16 + h) * 64 + dd) * Nseq + nn2] = f2bf(v);
                } else {
                    O[(size_t)m * 1024 + nn] = f2bf(v);
                }
            }
        }
}

// 64x64 core: 4 waves each 32x32 (2x2 frags), ping-pong, one barrier/iter.
// For gemm_out: grid 768 blocks = 3/CU.
__device__ __forceinline__
void gemm_core_sq(const ushortT* __restrict__ A, const ushortT* __restrict__ Bt,
                  int m0, int n0, ushortT* As, ushortT* Bs, f32x4 (&acc)[2][2])
{
    const int t = threadIdx.x;
    const int l = t & 63, w = t >> 6;
    const int wm = (w >> 1) * 32, wn = (w & 1) * 32;
    const int lm = l & 15, q = l >> 4;

    const int r0 = t >> 2, c0 = (t & 3) * 8;
    const ushortT* Ag = A  + (size_t)(m0 + r0) * 1024 + c0;
    const ushortT* Bg = Bt + (size_t)(n0 + r0) * 1024 + c0;
    ushortT* La = As + t * 8;
    ushortT* Lb = Bs + t * 8;

    gl2lds16(Ag, La);
    gl2lds16(Bg, Lb);

    for (int kt = 0; kt < 1024 / BK; ++kt) {
        __syncthreads();
        if (kt + 1 < 1024 / BK) {
            int ko = (kt + 1) * BK;
            int bo = ((kt + 1) & 1) ? 2048 : 0;
            gl2lds16(Ag + ko, La + bo);
            gl2lds16(Bg + ko, Lb + bo);
        }
        const ushortT* Ab = As + ((kt & 1) ? 2048 : 0);
        const ushortT* Bb = Bs + ((kt & 1) ? 2048 : 0);
        short8 af[2], bf[2];
#pragma unroll
        for (int i = 0; i < 2; ++i) {
            af[i] = *(const short8*)&Ab[(wm + i * 16 + lm) * 32 + q * 8];
            bf[i] = *(const short8*)&Bb[(wn + i * 16 + lm) * 32 + q * 8];
        }
#pragma unroll
        for (int i = 0; i < 2; ++i)
#pragma unroll
            for (int j = 0; j < 2; ++j)
                acc[i][j] = __builtin_amdgcn_mfma_f32_16x16x32_bf16(af[i], bf[j], acc[i][j], 0, 0, 0);
    }
}

// Output projection: AO bf16 @ WoT -> f32 out.  grid (16,48), 64x64 tiles.
__global__ __launch_bounds__(256)
void gemm_out(const ushortT* __restrict__ AO, const ushortT* __restrict__ WtO,
              const float* __restrict__ bias, float* __restrict__ C)
{
    __shared__ ushortT As[2 * 64 * 32];
    __shared__ ushortT Bs[2 * 64 * 32];
    const int m0 = blockIdx.y * 64, n0 = blockIdx.x * 64;

    f32x4 acc[2][2] = {};
    gemm_core_sq(AO, WtO, m0, n0, As, Bs, acc);

    const int t = threadIdx.x, l = t & 63, w = t >> 6;
    const int wm = (w >> 1) * 32, wn = (w & 1) * 32;
    const int lm = l & 15, q = l >> 4;
#pragma unroll
    for (int i = 0; i < 2; ++i)
#pragma unroll
        for (int j = 0; j < 2; ++j) {
            int n = n0 + wn + j * 16 + lm;
            float bn = bias[n];
#pragma unroll
            for (int r = 0; r < 4; ++r) {
                int m = m0 + wm + i * 16 + q * 4 + r;
                C[(size_t)m * 1024 + n] = acc[i][j][r] + bn;
            }
        }
}

// ---------------------------------------------------------------------------
// MFMA flash attention: 2 waves/block split the KEY dimension (parity-
// interleaved 64-key tiles; diagonal owned by parity-matching wave).  With
// m==0 (no max tracking) partial (l,t,O) over disjoint key sets sum exactly;
// merged once through LDS in the epilogue.  32 q-rows per block.
// ---------------------------------------------------------------------------
__global__ __launch_bounds__(128)
void attn_mfma(const ushortT* __restrict__ Q, const ushortT* __restrict__ K,
               const ushortT* __restrict__ Vt, const float* __restrict__ glogit,
               const float* __restrict__ bg2, ushortT* __restrict__ AO,
               float* __restrict__ ent)
{
    __shared__ ushortT Ps[2][32][72];
    __shared__ float mbuf[3072];        // 2048 oacc + 512 l + 512 t

    const int t  = threadIdx.x;
    const int w  = t >> 6, l = t & 63;
    const int ln = l & 15, q4 = l >> 4;
    const int bh = blockIdx.x, b = bh >> 4, h = bh & 15;
    const int q32 = (int)gridDim.y - 1 - (int)blockIdx.y;   // big-first
    const int wq = q32 * 32;
    const int kd = wq >> 6;                       // diagonal 64-key tile
    const int sbmax = ((wq >> 4) & 3) + 1;

    const ushortT* Qp = Q + (size_t)(b * Nseq + wq + ln) * Dmod + h * DHd + q4 * 8;
    short8 qf[2][2];
    qf[0][0] = *(const short8*)(Qp);
    qf[0][1] = *(const short8*)(Qp + 32);
    qf[1][0] = *(const short8*)(Qp + (size_t)16 * Dmod);
    qf[1][1] = *(const short8*)(Qp + (size_t)16 * Dmod + 32);

    float l_lane[2][4] = {}, t_lane[2][4] = {};
    f32x4 oacc[2][4] = {};

    const ushortT* Kbase = K  + (size_t)(b * Nseq) * Dmod + h * DHd + q4 * 8;
    const ushortT* Vbase = Vt + ((size_t)(b * 16 + h) * 64) * Nseq + q4 * 8;

    short8 kc[4][2];
    {
        const ushortT* Kp = Kbase + (size_t)(w * 64 + ln) * Dmod;
#pragma unroll
        for (int nb = 0; nb < 4; ++nb) {
            kc[nb][0] = *(const short8*)(Kp + (size_t)nb * 16 * Dmod);
            kc[nb][1] = *(const short8*)(Kp + (size_t)nb * 16 * Dmod + 32);
        }
    }

    for (int kt = w; kt < kd; kt += 2) {
        const int k0 = kt * 64;
        const ushortT* Vp = Vbase + (size_t)ln * Nseq + k0;
        short8 vf[4][2];
#pragma unroll
        for (int nb = 0; nb < 4; ++nb) {
            vf[nb][0] = *(const short8*)(Vp + (size_t)nb * 16 * Nseq);
            vf[nb][1] = *(const short8*)(Vp + (size_t)nb * 16 * Nseq + 32);
        }
        short8 kn[4][2];
        {
            int prow = k0 + 128; if (prow > Nseq - 64) prow = Nseq - 64;
            const ushortT* Kp = Kbase + (size_t)(prow + ln) * Dmod;
#pragma unroll
            for (int nb = 0; nb < 4; ++nb) {
                kn[nb][0] = *(const short8*)(Kp + (size_t)nb * 16 * Dmod);
                kn[nb][1] = *(const short8*)(Kp + (size_t)nb * 16 * Dmod + 32);
            }
        }
        f32x4 sacc[2][4];
#pragma unroll
        for (int g = 0; g < 2; ++g)
#pragma unroll
            for (int nb = 0; nb < 4; ++nb) {
                f32x4 a = {};
                a = __builtin_amdgcn_mfma_f32_16x16x32_bf16(qf[g][0], kc[nb][0], a, 0, 0, 0);
                a = __builtin_amdgcn_mfma_f32_16x16x32_bf16(qf[g][1], kc[nb][1], a, 0, 0, 0);
                sacc[g][nb] = a;
            }
#pragma unroll
        for (int g = 0; g < 2; ++g)
#pragma unroll
            for (int nb = 0; nb < 4; ++nb)
#pragma unroll
                for (int r = 0; r < 4; ++r) {
                    float sv = sacc[g][nb][r];
                    float ev = __expf(sv);
                    l_lane[g][r] += ev;
                    t_lane[g][r] += ev * sv;
                    Ps[w][g * 16 + q4 * 4 + r][nb * 16 + ln] = f2bf(ev);
                }
        short8 pf[2][2];
#pragma unroll
        for (int g = 0; g < 2; ++g) {
            pf[g][0] = *(const short8*)&Ps[w][g * 16 + ln][q4 * 8];
            pf[g][1] = *(const short8*)&Ps[w][g * 16 + ln][32 + q4 * 8];
        }
#pragma unroll
        for (int g = 0; g < 2; ++g)
#pragma unroll
            for (int nb = 0; nb < 4; ++nb) {
                oacc[g][nb] = __builtin_amdgcn_mfma_f32_16x16x32_bf16(pf[g][0], vf[nb][0], oacc[g][nb], 0, 0, 0);
                oacc[g][nb] = __builtin_amdgcn_mfma_f32_16x16x32_bf16(pf[g][1], vf[nb][1], oacc[g][nb], 0, 0, 0);
            }
#pragma unroll
        for (int nb = 0; nb < 4; ++nb) { kc[nb][0] = kn[nb][0]; kc[nb][1] = kn[nb][1]; }
    }

    // ---- diagonal tile: owned by the wave whose parity matches kd ----
    if ((kd & 1) == w) {
        const int k0 = kd * 64;
        const ushortT* Vp = Vbase + (size_t)ln * Nseq + k0;
        short8 vf[4][2];
#pragma unroll
        for (int nb = 0; nb < 4; ++nb) {
            vf[nb][0] = *(const short8*)(Vp + (size_t)nb * 16 * Nseq);
            vf[nb][1] = *(const short8*)(Vp + (size_t)nb * 16 * Nseq + 32);
        }
        f32x4 sacc[2][4];
#pragma unroll
        for (int g = 0; g < 2; ++g)
#pragma unroll
            for (int nb = 0; nb < 4; ++nb)
                if (nb <= sbmax) {
                    f32x4 a = {};
                    a = __builtin_amdgcn_mfma_f32_16x16x32_bf16(qf[g][0], kc[nb][0], a, 0, 0, 0);
                    a = __builtin_amdgcn_mfma_f32_16x16x32_bf16(qf[g][1], kc[nb][1], a, 0, 0, 0);
                    sacc[g][nb] = a;
                }
#pragma unroll
        for (int g = 0; g < 2; ++g)
#pragma unroll
            for (int nb = 0; nb < 4; ++nb)
#pragma unroll
                for (int r = 0; r < 4; ++r) {
                    float ev = 0.f;
                    if (nb <= sbmax) {
                        int kg = k0 + nb * 16 + ln;
                        int qg = wq + g * 16 + q4 * 4 + r;
                        float sv = sacc[g][nb][r];
                        ev = (kg <= qg) ? __expf(sv) : 0.f;
                        l_lane[g][r] += ev;
                        t_lane[g][r] += ev * sv;
                    }
                    Ps[w][g * 16 + q4 * 4 + r][nb * 16 + ln] = f2bf(ev);
                }
        short8 pf[2][2];
#pragma unroll
        for (int g = 0; g < 2; ++g) {
            pf[g][0] = *(const short8*)&Ps[w][g * 16 + ln][q4 * 8];
            pf[g][1] = *(const short8*)&Ps[w][g * 16 + ln][32 + q4 * 8];
        }
#pragma unroll
        for (int g = 0; g < 2; ++g)
#pragma unroll
            for (int nb = 0; nb < 4; ++nb) {
                oacc[g][nb] = __builtin_amdgcn_mfma_f32_16x16x32_bf16(pf[g][0], vf[nb][0], oacc[g][nb], 0, 0, 0);
                oacc[g][nb] = __builtin_amdgcn_mfma_f32_16x16x32_bf16(pf[g][1], vf[nb][1], oacc[g][nb], 0, 0, 0);
            }
    }

    // ---- merge wave1 partials into wave0 (exact: disjoint key sets, m==0) ----
    if (w == 1) {
#pragma unroll
        for (int g = 0; g < 2; ++g)
#pragma unroll
            for (int nb = 0; nb < 4; ++nb)
#pragma unroll
                for (int r = 0; r < 4; ++r)
                    mbuf[(((g << 2) | nb) * 4 + r) * 64 + l] = oacc[g][nb][r];
#pragma unroll
        for (int g = 0; g < 2; ++g)
#pragma unroll
            for (int r = 0; r < 4; ++r) {
                mbuf[2048 + ((g << 2) | r) * 64 + l] = l_lane[g][r];
                mbuf[2560 + ((g << 2) | r) * 64 + l] = t_lane[g][r];
            }
    }
    __syncthreads();
    if (w == 1) return;
#pragma unroll
    for (int g = 0; g < 2; ++g) {
#pragma unroll
        for (int nb = 0; nb < 4; ++nb)
#pragma unroll
            for (int r = 0; r < 4; ++r)
                oacc[g][nb][r] += mbuf[(((g << 2) | nb) * 4 + r) * 64 + l];
#pragma unroll
        for (int r = 0; r < 4; ++r) {
            l_lane[g][r] += mbuf[2048 + ((g << 2) | r) * 64 + l];
            t_lane[g][r] += mbuf[2560 + ((g << 2) | r) * 64 + l];
        }
    }

    // ---- epilogue (wave 0 only) ----
    const float bg2v = bg2[0];
#pragma unroll
    for (int g = 0; g < 2; ++g) {
        float sc[4];
#pragma unroll
        for (int r = 0; r < 4; ++r) {
            float lv = l_lane[g][r], tv = t_lane[g][r];
#pragma unroll
            for (int msk = 1; msk < 16; msk <<= 1) {
                lv += __shfl_xor(lv, msk, 16);
                tv += __shfl_xor(tv, msk, 16);
            }
            int qg = wq + g * 16 + q4 * 4 + r;
            float inv = 1.f / lv;
            if (ln == 0)
                ent[((size_t)b * NH + h) * Nseq + qg] = logf(lv) - tv * inv;
            float logit = glogit[b * Nseq + qg] + bg2v;
            sc[r] = inv / (1.f + __expf(-logit));
        }
#pragma unroll
        for (int nb = 0; nb < 4; ++nb)
#pragma unroll
            for (int r = 0; r < 4; ++r) {
                int qg = wq + g * 16 + q4 * 4 + r;
                AO[(size_t)(b * Nseq + qg) * Dmod + h * DHd + nb * 16 + ln] =
                    f2bf(oacc[g][nb][r] * sc[r]);
            }
    }
}

// ---------------------------------------------------------------------------
extern "C" void kernel_launch(void* const* d_in, const int* in_sizes, int n_in,
                              void* d_out, int out_size, void* d_ws, size_t ws_size,
                              hipStream_t stream)
{
    const float* x   = (const float*)d_in[0];
    const float* Wq  = (const float*)d_in[2];
    const float* bq  = (const float*)d_in[3];
    const float* Wk  = (const float*)d_in[4];
    const float* bk  = (const float*)d_in[5];
    const float* Wv  = (const float*)d_in[6];
    const float* bv  = (const float*)d_in[7];
    const float* Wg1 = (const float*)d_in[8];
    const float* bg1 = (const float*)d_in[9];
    const float* Wg2 = (const float*)d_in[10];
    const float* bg2 = (const float*)d_in[11];
    const float* Wo  = (const float*)d_in[12];
    const float* bo  = (const float*)d_in[13];

    const size_t NE = (size_t)MTOT * Dmod;
    ushortT* p   = (ushortT*)d_ws;
    ushortT* Qw  = p; p += NE;
    ushortT* Kw  = p; p += NE;
    ushortT* Vtw = p; p += NE;       // V transposed: [B,H,64,Nseq]
    ushortT* AO  = p; p += NE;
    ushortT* xb  = p; p += NE;
    ushortT* WtQ = p; p += (size_t)1024 * 1024;   // WtQ|WtK|WtV|WtG contiguous = fused B [4096][1024]
    ushortT* WtK = p; p += (size_t)1024 * 1024;
    ushortT* WtV = p; p += (size_t)1024 * 1024;
    ushortT* WtG = p; p += (size_t)1024 * 1024;
    ushortT* WtO = p; p += (size_t)1024 * 1024;
    float* glogit = (float*)p;       // MTOT floats

    float* out_f = (float*)d_out;
    float* ent_f = out_f + NE;

    prep_kernel<<<dim3(16, 16, 6), 256, 0, stream>>>(Wq, Wk, Wv, Wg1, Wo,
                                                     WtQ, WtK, WtV, WtG, WtO,
                                                     x, xb, glogit);
    gemm_qkvg<<<dim3(16, 12), 512, 0, stream>>>(xb, WtQ,
                                                bq, bk, bv, bg1, Wg2,
                                                Qw, Kw, Vtw, glogit);
    attn_mfma<<<dim3(Bsz * NH, Nseq / 32), 128, 0, stream>>>(Qw, Kw, Vtw, glogit,
                                                             bg2, AO, ent_f);
    gemm_out<<<dim3(16, 48), 256, 0, stream>>>(AO, WtO, bo, out_f);
}